// Round 4
// baseline (247.216 us; speedup 1.0000x reference)
//
#include <hip/hip_runtime.h>

// ---------------- problem constants ----------------
#define BATCH 512
#define SDIM  680          // i dimension (680)
#define DIP   768          // i padded to 768 = 24*32 = 6*128
#define ABC   55296        // 48*24*48
#define NB_   24
#define SQRT2F 1.4142135623730951f

typedef __attribute__((ext_vector_type(8))) short bf16x8;
typedef __attribute__((ext_vector_type(4))) float f32x4;

// ws layout (bytes)
#define DP_BYTES   ((size_t)ABC * DIP * 2)            // 84,934,656
#define DPT_BYTES  ((size_t)DIP * ABC * 2)            // 84,934,656
#define FP_BYTES   ((size_t)BATCH * DIP * 2)          //    786,432
#define G_BYTES    ((size_t)BATCH * ABC * 2)          // 56,623,104
#define DP_OFF     ((size_t)0)
#define DPT_OFF    (DP_OFF + DP_BYTES)
#define FP_OFF     (DPT_OFF + DPT_BYTES)
#define G_OFF      (FP_OFF + FP_BYTES)
#define WS_NEEDED  (G_OFF + G_BYTES)                  // 227,278,848

// gemm2 split-K config: 55296 = 54 * 1024
#define SPLITK 54
#define KC     1024
// partials P[SPLITK][512][768] f32 = 84,934,656 B == DP_BYTES, overlays Dp
// (dead after gemm1; stream order serializes).
#define P_OFF  DP_OFF

__device__ __forceinline__ unsigned short f2bf(float f) {
  unsigned int u = __float_as_uint(f);
  unsigned int r = (u + 0x7FFFu + ((u >> 16) & 1u)) >> 16;   // RNE
  return (unsigned short)r;
}

__device__ __forceinline__ void stage16(const void* g, const void* l) {
  __builtin_amdgcn_global_load_lds(
      (const __attribute__((address_space(1))) unsigned int*)g,
      (__attribute__((address_space(3))) unsigned int*)l, 16, 0, 0);
}

// ---------------- convert D -> Dp [ABC][DIP] bf16 and DpT [DIP][ABC] bf16 ----------------
// Register-resident 4x4 transpose: no LDS, no sync, fully vectorized.
// grid 864 (abc tiles of 64) * 12 (i tiles of 64), 256 threads; thread = 4x4 subtile.
__global__ __launch_bounds__(256) void convert_d(const float* __restrict__ D,
                                                 unsigned short* __restrict__ Dp,
                                                 unsigned short* __restrict__ DpT) {
  const int b = blockIdx.x;
  const int bx = b % 864;            // abc tile
  const int by = b / 864;            // i tile
  const int t = threadIdx.x;
  const int rr = t >> 4, cc = t & 15;
  const int r0 = bx * 64 + rr * 4;   // abc row base (always < 55296)
  const int c0 = by * 64 + cc * 4;   // i col base

  float4 v[4];
  const bool valid = c0 < SDIM;      // float4 spans c0..c0+3; max valid start 676
  #pragma unroll
  for (int dr = 0; dr < 4; ++dr)
    v[dr] = valid ? *(const float4*)(D + (size_t)(r0 + dr) * SDIM + c0)
                  : make_float4(0.f, 0.f, 0.f, 0.f);
  const float* fv = reinterpret_cast<const float*>(v);

  // Dp rows (direct layout): wave covers full 128B lines
  #pragma unroll
  for (int dr = 0; dr < 4; ++dr) {
    ushort4 p;
    p.x = f2bf(fv[dr * 4 + 0]); p.y = f2bf(fv[dr * 4 + 1]);
    p.z = f2bf(fv[dr * 4 + 2]); p.w = f2bf(fv[dr * 4 + 3]);
    *(ushort4*)(Dp + (size_t)(r0 + dr) * DIP + c0) = p;
  }
  // DpT rows (transposed in registers): 32B segments; block's 4 waves complete
  // each 128B line, L2 write-back merges before HBM eviction.
  #pragma unroll
  for (int j = 0; j < 4; ++j) {
    ushort4 p;
    p.x = f2bf(fv[0 * 4 + j]); p.y = f2bf(fv[1 * 4 + j]);
    p.z = f2bf(fv[2 * 4 + j]); p.w = f2bf(fv[3 * 4 + j]);
    *(ushort4*)(DpT + (size_t)(c0 + j) * ABC + r0) = p;
  }
}

// ---------------- convert F -> Fp [BATCH][DIP] bf16 ----------------
__global__ __launch_bounds__(256) void convert_f(const float* __restrict__ F,
                                                 unsigned short* __restrict__ Fp) {
  const int u = blockIdx.x * 256 + threadIdx.x;
  if (u >= BATCH * (DIP / 8)) return;
  const int n = u / (DIP / 8), s = u % (DIP / 8);
  const int i = s * 8;
  float4 a = make_float4(0.f, 0.f, 0.f, 0.f), b = a;
  if (i < SDIM) {
    a = *(const float4*)(F + (size_t)n * SDIM + i);
    b = *(const float4*)(F + (size_t)n * SDIM + i + 4);
  }
  uint4 p;
  p.x = f2bf(a.x) | ((unsigned int)f2bf(a.y) << 16);
  p.y = f2bf(a.z) | ((unsigned int)f2bf(a.w) << 16);
  p.z = f2bf(b.x) | ((unsigned int)f2bf(b.y) << 16);
  p.w = f2bf(b.z) | ((unsigned int)f2bf(b.w) << 16);
  *(uint4*)(Fp + (size_t)n * DIP + i) = p;
}

// ---------------- GEMM1: G[n][abc] = relu(F·D^T)·sqrt2·qw[b]  (bf16 out) ----------------
__global__ __launch_bounds__(256) void gemm1(const unsigned short* __restrict__ Fp,
                                             const unsigned short* __restrict__ Dp,
                                             const float* __restrict__ qw,
                                             unsigned short* __restrict__ G) {
  __shared__ short At[2][128 * 32];
  __shared__ short Bt[2][128 * 32];
  __shared__ float qws[NB_];
  const int t = threadIdx.x;
  const int bid = blockIdx.x;            // 1728 = 8 XCD * 216
  const int logical = (bid & 7) * 216 + (bid >> 3);
  const int nt = logical >> 2, mt = logical & 3;
  const int m0 = mt * 128, n0 = nt * 128;
  if (t < NB_) qws[t] = qw[t] * SQRT2F;

  const int rowu = t >> 2, k8 = (t & 3) * 8;
  const unsigned short* Ab = Fp + (size_t)(m0 + rowu) * DIP + k8;
  const unsigned short* Bb = Dp + (size_t)(n0 + rowu) * DIP + k8;

  const int lane = t & 63, wid = t >> 6;
  const int wm = wid >> 1, wn = wid & 1;
  const int fr = lane & 15, fk = lane >> 4;

  f32x4 acc[4][4];
  #pragma unroll
  for (int i = 0; i < 4; ++i)
    #pragma unroll
    for (int j = 0; j < 4; ++j)
      #pragma unroll
      for (int k = 0; k < 4; ++k) acc[i][j][k] = 0.f;

  auto stage = [&](int b, int kk) {
    const unsigned short* ga = Ab + kk * 32;
    const unsigned short* gb = Bb + kk * 32;
    stage16(ga,            &At[b][t * 8]);
    stage16(ga + 64 * DIP, &At[b][(t + 256) * 8]);
    stage16(gb,            &Bt[b][t * 8]);
    stage16(gb + 64 * DIP, &Bt[b][(t + 256) * 8]);
  };

  stage(0, 0);
  __syncthreads();
  const int KS = DIP / 32;   // 24
  for (int ks = 0; ks < KS; ++ks) {
    const int cur = ks & 1;
    if (ks + 1 < KS) stage(cur ^ 1, ks + 1);
    bf16x8 af[4], bv[4];
    #pragma unroll
    for (int mi = 0; mi < 4; ++mi)
      af[mi] = *(const bf16x8*)&At[cur][(wm * 64 + mi * 16 + fr) * 32 + fk * 8];
    #pragma unroll
    for (int ni = 0; ni < 4; ++ni)
      bv[ni] = *(const bf16x8*)&Bt[cur][(wn * 64 + ni * 16 + fr) * 32 + fk * 8];
    #pragma unroll
    for (int mi = 0; mi < 4; ++mi)
      #pragma unroll
      for (int ni = 0; ni < 4; ++ni)
        acc[mi][ni] = __builtin_amdgcn_mfma_f32_16x16x32_bf16(af[mi], bv[ni], acc[mi][ni], 0, 0, 0);
    __syncthreads();
  }

  #pragma unroll
  for (int mi = 0; mi < 4; ++mi) {
    const int gm0 = m0 + wm * 64 + mi * 16 + fk * 4;
    #pragma unroll
    for (int ni = 0; ni < 4; ++ni) {
      const int gc = n0 + wn * 64 + ni * 16 + fr;
      const float qv = qws[(gc / 48) % NB_];
      #pragma unroll
      for (int r = 0; r < 4; ++r) {
        const float v = fmaxf(acc[mi][ni][r], 0.f) * qv;
        G[(size_t)(gm0 + r) * ABC + gc] = f2bf(v);
      }
    }
  }
}

// ---------------- GEMM2: P[sk][n][i] = sum_{k in chunk sk} G[n][k] * DpT[i][k] ----------------
// Deterministic split-K, no atomics. 54 chunks of 1024 (32 K-steps).
__global__ __launch_bounds__(256) void gemm2(const unsigned short* __restrict__ Gm,
                                             const unsigned short* __restrict__ DpT,
                                             float* __restrict__ P) {
  __shared__ short At[2][128 * 32];
  __shared__ short Bt[2][128 * 32];
  const int t = threadIdx.x;
  const int bid = blockIdx.x;            // 1296 = 8 XCD * 162
  const int logical = (bid & 7) * 162 + (bid >> 3);
  const int sk = logical / 24;
  const int rem = logical % 24;
  const int nt = rem >> 2, mt = rem & 3;
  const int m0 = mt * 128, n0 = nt * 128;
  const size_t kbase = (size_t)sk * KC;

  const int rowu = t >> 2, k8 = (t & 3) * 8;
  const unsigned short* Ab = Gm  + (size_t)(m0 + rowu) * ABC + kbase + k8;
  const unsigned short* Bb = DpT + (size_t)(n0 + rowu) * ABC + kbase + k8;

  const int lane = t & 63, wid = t >> 6;
  const int wm = wid >> 1, wn = wid & 1;
  const int fr = lane & 15, fk = lane >> 4;

  f32x4 acc[4][4];
  #pragma unroll
  for (int i = 0; i < 4; ++i)
    #pragma unroll
    for (int j = 0; j < 4; ++j)
      #pragma unroll
      for (int k = 0; k < 4; ++k) acc[i][j][k] = 0.f;

  auto stage = [&](int b, int kk) {
    const unsigned short* ga = Ab + kk * 32;
    const unsigned short* gb = Bb + kk * 32;
    stage16(ga,                    &At[b][t * 8]);
    stage16(ga + (size_t)64 * ABC, &At[b][(t + 256) * 8]);
    stage16(gb,                    &Bt[b][t * 8]);
    stage16(gb + (size_t)64 * ABC, &Bt[b][(t + 256) * 8]);
  };

  stage(0, 0);
  __syncthreads();
  const int KS = KC / 32;   // 32
  for (int ks = 0; ks < KS; ++ks) {
    const int cur = ks & 1;
    if (ks + 1 < KS) stage(cur ^ 1, ks + 1);
    bf16x8 af[4], bv[4];
    #pragma unroll
    for (int mi = 0; mi < 4; ++mi)
      af[mi] = *(const bf16x8*)&At[cur][(wm * 64 + mi * 16 + fr) * 32 + fk * 8];
    #pragma unroll
    for (int ni = 0; ni < 4; ++ni)
      bv[ni] = *(const bf16x8*)&Bt[cur][(wn * 64 + ni * 16 + fr) * 32 + fk * 8];
    #pragma unroll
    for (int mi = 0; mi < 4; ++mi)
      #pragma unroll
      for (int ni = 0; ni < 4; ++ni)
        acc[mi][ni] = __builtin_amdgcn_mfma_f32_16x16x32_bf16(af[mi], bv[ni], acc[mi][ni], 0, 0, 0);
    __syncthreads();
  }

  float* Pb = P + (size_t)sk * BATCH * DIP;
  #pragma unroll
  for (int mi = 0; mi < 4; ++mi) {
    const int gm0 = m0 + wm * 64 + mi * 16 + fk * 4;
    #pragma unroll
    for (int ni = 0; ni < 4; ++ni) {
      const int gi = n0 + wn * 64 + ni * 16 + fr;
      #pragma unroll
      for (int r = 0; r < 4; ++r)
        Pb[(size_t)(gm0 + r) * DIP + gi] = acc[mi][ni][r];
    }
  }
}

// ---------------- reduce: out[n][i] = sum_s P[s][n][i]  (i < 680) ----------------
// float2 units: 174080 threads = 680 blocks (2.7 blocks/CU for latency hiding).
__global__ __launch_bounds__(256) void reduce_p(const float* __restrict__ P,
                                                float* __restrict__ out) {
  const int u = blockIdx.x * 256 + threadIdx.x;   // 512 * 340
  const int n = u / (SDIM / 2), q = u % (SDIM / 2);
  const int i = q * 2;
  const float* base = P + (size_t)n * DIP + i;
  const size_t stride = (size_t)BATCH * DIP;
  float2 a0 = make_float2(0.f, 0.f), a1 = a0, a2 = a0, a3 = a0, a4 = a0, a5 = a0;
  #pragma unroll 3
  for (int s = 0; s < SPLITK; s += 6) {
    float2 v0 = *(const float2*)(base + (size_t)(s + 0) * stride);
    float2 v1 = *(const float2*)(base + (size_t)(s + 1) * stride);
    float2 v2 = *(const float2*)(base + (size_t)(s + 2) * stride);
    float2 v3 = *(const float2*)(base + (size_t)(s + 3) * stride);
    float2 v4 = *(const float2*)(base + (size_t)(s + 4) * stride);
    float2 v5 = *(const float2*)(base + (size_t)(s + 5) * stride);
    a0.x += v0.x; a0.y += v0.y;
    a1.x += v1.x; a1.y += v1.y;
    a2.x += v2.x; a2.y += v2.y;
    a3.x += v3.x; a3.y += v3.y;
    a4.x += v4.x; a4.y += v4.y;
    a5.x += v5.x; a5.y += v5.y;
  }
  float2 r;
  r.x = ((a0.x + a1.x) + (a2.x + a3.x)) + (a4.x + a5.x);
  r.y = ((a0.y + a1.y) + (a2.y + a3.y)) + (a4.y + a5.y);
  *(float2*)(out + (size_t)n * SDIM + i) = r;
}

// ---------------- fallback (no workspace needed): slow but correct ----------------
__global__ __launch_bounds__(256) void so3_fallback(const float* __restrict__ F,
                                                    const float* __restrict__ D,
                                                    const float* __restrict__ qw,
                                                    float* __restrict__ out) {
  const int n = blockIdx.x;
  __shared__ float fsh[SDIM];
  __shared__ float acc[SDIM];
  __shared__ float gch[256];
  for (int i = threadIdx.x; i < SDIM; i += 256) {
    fsh[i] = F[(size_t)n * SDIM + i];
    acc[i] = 0.f;
  }
  __syncthreads();
  for (int c0 = 0; c0 < ABC; c0 += 256) {
    const int r = c0 + threadIdx.x;
    const float* dr = D + (size_t)r * SDIM;
    float s = 0.f;
    for (int i = 0; i < SDIM; ++i) s += fsh[i] * dr[i];
    s = fmaxf(s, 0.f) * SQRT2F * qw[(r / 48) % NB_];
    gch[threadIdx.x] = s;
    __syncthreads();
    for (int i = threadIdx.x; i < SDIM; i += 256) {
      float a = 0.f;
      for (int tt = 0; tt < 256; ++tt) a += gch[tt] * D[(size_t)(c0 + tt) * SDIM + i];
      acc[i] += a;
    }
    __syncthreads();
  }
  for (int i = threadIdx.x; i < SDIM; i += 256) out[(size_t)n * SDIM + i] = acc[i];
}

// ---------------- launch ----------------
extern "C" void kernel_launch(void* const* d_in, const int* in_sizes, int n_in,
                              void* d_out, int out_size, void* d_ws, size_t ws_size,
                              hipStream_t stream) {
  const float* F  = (const float*)d_in[0];
  const float* D  = (const float*)d_in[1];
  const float* qw = (const float*)d_in[2];
  float* out = (float*)d_out;

  if (ws_size < WS_NEEDED) {
    so3_fallback<<<BATCH, 256, 0, stream>>>(F, D, qw, out);
    return;
  }

  unsigned short* Dp  = (unsigned short*)((char*)d_ws + DP_OFF);
  unsigned short* DpT = (unsigned short*)((char*)d_ws + DPT_OFF);
  unsigned short* Fp  = (unsigned short*)((char*)d_ws + FP_OFF);
  unsigned short* G   = (unsigned short*)((char*)d_ws + G_OFF);
  float*          P   = (float*)((char*)d_ws + P_OFF);   // overlays Dp (dead after gemm1)

  convert_d<<<864 * 12, 256, 0, stream>>>(D, Dp, DpT);
  convert_f<<<192, 256, 0, stream>>>(F, Fp);
  gemm1<<<432 * 4, 256, 0, stream>>>(Fp, Dp, qw, G);
  gemm2<<<SPLITK * 24, 256, 0, stream>>>(G, DpT, P);
  reduce_p<<<680, 256, 0, stream>>>(P, out);
}